// Round 10
// baseline (1565.266 us; speedup 1.0000x reference)
//
#include <hip/hip_runtime.h>

typedef float f32x16 __attribute__((ext_vector_type(16)));
typedef int   i32x8  __attribute__((ext_vector_type(8)));
typedef int   i32x4  __attribute__((ext_vector_type(4)));
typedef unsigned char uchar;

#define KEPS 1e-8f
#define BM 128
#define BN 128
#define BK 64    // one K=64 scaled-MFMA step per kt; 16 K-iterations

// ---------------- 1) row L2-normalize: fp32 norms + fp8 e4m3 copy -----------
__global__ __launch_bounds__(256) void k_normalize(
    const float* __restrict__ in, uchar* __restrict__ xq,
    float* __restrict__ norms, unsigned long long* __restrict__ best,
    float* __restrict__ psum, int D)
{
    const int row = blockIdx.x;
    const int t = threadIdx.x;
    const float4* inr = (const float4*)(in + (size_t)row * D);
    float4 v = inr[t];                       // D=1024 -> 256 float4
    float ss = v.x*v.x + v.y*v.y + v.z*v.z + v.w*v.w;
    for (int off = 32; off; off >>= 1) ss += __shfl_down(ss, off);
    __shared__ float red[4];
    const int lane = t & 63, wave = t >> 6;
    if (lane == 0) red[wave] = ss;
    __syncthreads();
    const float total = red[0] + red[1] + red[2] + red[3];
    const float nrm = sqrtf(total);
    const float inv = 1.0f / fmaxf(nrm, KEPS);
    unsigned r = 0;
    r = __builtin_amdgcn_cvt_pk_fp8_f32(v.x * inv, v.y * inv, r, 0);
    r = __builtin_amdgcn_cvt_pk_fp8_f32(v.z * inv, v.w * inv, r, 1);
    ((unsigned*)(xq + (size_t)row * D))[t] = r;
    if (t == 0) {
        norms[row] = nrm;
        best[row] = 0ull;                    // any real packed key beats 0
    }
    if (row < 256 && t == 1) psum[row * 16] = 0.0f;   // cache-line-padded partials
}

__device__ __forceinline__ unsigned long long pack_key(float v, unsigned idx)
{
    unsigned ub = __float_as_uint(v);
    ub = (ub & 0x80000000u) ? ~ub : (ub | 0x80000000u); // monotonic map
    return ((unsigned long long)ub << 32) | (unsigned long long)(~idx);
}

// ---------------- 2) x x^T triangular MX-fp8 GEMM, dbuf LDS, 4 blocks/CU ----
// Same geometry as R9 (BM=BN=128, BK=64, dbuf 32 KiB, 4 blocks/CU, 4 waves
// each owning 64x64) but the inner compute is mfma_scale_f32_32x32x64_f8f6f4
// with unit scales (e8m0=127 -> 2^0): 2x the non-scaled fp8 rate, one
// instruction per 32x32 tile per kt -> 4 MFMA + 8 ds_read_b128 per kt
// (was 32 MFMA + 16 ds_read_b64).
// A/B fragment: m(n)=lane&31, k = (lane>>5)*32 + byte (natural extension of
// the non-scaled 32x32 family). C/D (m74/m101-verified, shape-determined):
// col=lane&31, row=(reg&3)+8*(reg>>2)+4*(lane>>5).
// Triangular covering bx >= by; row-pass + col-pass (off-diag) covers every
// unordered pair; duplicates harmless under idempotent atomicMax.
__global__ __launch_bounds__(256, 4) void k_gemm_argmax(
    const uchar* __restrict__ xq, unsigned long long* __restrict__ best,
    int T)
{
    // triangular mapping: p -> (by, bx), bx >= by
    const int p = blockIdx.x;
    const float tf = (float)T + 0.5f;
    int by = (int)(tf - sqrtf(tf * tf - 2.0f * (float)p));
    while (by > 0 && p < by * T - by * (by - 1) / 2) --by;
    while (p >= (by + 1) * T - (by + 1) * by / 2) ++by;
    const int bx = by + (p - (by * T - by * (by - 1) / 2));

    __shared__ uchar lds[2][(BM + BN) * BK];   // 2 x 16 KiB
    const int t    = threadIdx.x;
    const int lane = t & 63;
    const int wave = t >> 6;
    const int m    = lane & 31;
    const int half = lane >> 5;
    const int wrow = (wave >> 1) * 64;
    const int wcol = (wave & 1) * 64;
    const int m0   = by * BM;
    const int n0   = bx * BN;

    f32x16 acc[2][2] = {};

    // staging: thread t owns stored chunk c = t (rows 0..63) and c = t + 256
    // (rows 64..127) of each panel; stored col = t&3, global col swizzled.
    const int row_s = t >> 2;
    const int col_s = t & 3;
    const int gsw = (col_s ^ ((row_s ^ (row_s >> 2)) & 3)) * 16;  // byte col
    const uchar* aP0 = xq + (size_t)(m0 + row_s) * 1024 + gsw;
    const uchar* bP0 = xq + (size_t)(n0 + row_s) * 1024 + gsw;
    const uchar* aP1 = aP0 + 64 * 1024;
    const uchar* bP1 = bP0 + 64 * 1024;
    const int l16 = t * 16;

#define STAGE(buf, koff)                                                              \
    do {                                                                              \
        __builtin_amdgcn_global_load_lds(                                             \
            (const __attribute__((address_space(1))) void*)(aP0 + (koff)),            \
            (__attribute__((address_space(3))) void*)(&lds[buf][0] + l16), 16, 0, 0); \
        __builtin_amdgcn_global_load_lds(                                             \
            (const __attribute__((address_space(1))) void*)(aP1 + (koff)),            \
            (__attribute__((address_space(3))) void*)(&lds[buf][4096] + l16), 16, 0, 0); \
        __builtin_amdgcn_global_load_lds(                                             \
            (const __attribute__((address_space(1))) void*)(bP0 + (koff)),            \
            (__attribute__((address_space(3))) void*)(&lds[buf][8192] + l16), 16, 0, 0); \
        __builtin_amdgcn_global_load_lds(                                             \
            (const __attribute__((address_space(1))) void*)(bP1 + (koff)),            \
            (__attribute__((address_space(3))) void*)(&lds[buf][12288] + l16), 16, 0, 0); \
    } while (0)

    STAGE(0, 0);
    __syncthreads();

    const unsigned sc1 = 0x7F7F7F7Fu;    // e8m0 = 127 -> scale 2^0 = 1.0

    #pragma unroll
    for (int kt = 0; kt < 16; ++kt) {
        const int cur = kt & 1;
        if (kt < 15) STAGE(cur ^ 1, (kt + 1) * BK);   // K-advance in pointer
        const uchar* Al = &lds[cur][0];
        const uchar* Bl = &lds[cur][8192];
        i32x8 a[2], b[2];
        #pragma unroll
        for (int i = 0; i < 2; ++i) {
            const int row = wrow + i * 32 + m;
            const int sw  = (row ^ (row >> 2)) & 3;
            const uchar* base = Al + row * 64;
            const i32x4 lo = *(const i32x4*)(base + (((2 * half)     ^ sw) * 16));
            const i32x4 hi = *(const i32x4*)(base + (((2 * half + 1) ^ sw) * 16));
            a[i] = i32x8{lo.x, lo.y, lo.z, lo.w, hi.x, hi.y, hi.z, hi.w};
        }
        #pragma unroll
        for (int j = 0; j < 2; ++j) {
            const int row = wcol + j * 32 + m;
            const int sw  = (row ^ (row >> 2)) & 3;
            const uchar* base = Bl + row * 64;
            const i32x4 lo = *(const i32x4*)(base + (((2 * half)     ^ sw) * 16));
            const i32x4 hi = *(const i32x4*)(base + (((2 * half + 1) ^ sw) * 16));
            b[j] = i32x8{lo.x, lo.y, lo.z, lo.w, hi.x, hi.y, hi.z, hi.w};
        }
        #pragma unroll
        for (int i = 0; i < 2; ++i)
            #pragma unroll
            for (int j = 0; j < 2; ++j)
                acc[i][j] = __builtin_amdgcn_mfma_scale_f32_32x32x64_f8f6f4(
                    a[i], b[j], acc[i][j], 0 /*cbsz: fp8*/, 0 /*blgp: fp8*/,
                    0, sc1, 0, sc1);
        __syncthreads();
    }
#undef STAGE

    // ---- row-wise argmax (this wave's 64 rows, over its 64 cols) ----
    // C/D: col = lane&31, row = (reg&3) + 8*(reg>>2) + 4*half.
    #pragma unroll
    for (int i = 0; i < 2; ++i) {
        #pragma unroll
        for (int reg = 0; reg < 16; ++reg) {
            const int grow = m0 + wrow + i * 32 + (reg & 3) + 8 * (reg >> 2) + 4 * half;
            float v = -3.0f; unsigned c = 0xFFFFFFFFu;
            #pragma unroll
            for (int j = 0; j < 2; ++j) {
                const int col = n0 + wcol + j * 32 + m;
                const float val = acc[i][j][reg];
                if (col != grow && (val > v || (val == v && (unsigned)col < c))) {
                    v = val; c = (unsigned)col;
                }
            }
            // reduce across the 32 lanes of this half (xor<32 keeps half)
            for (int off = 16; off; off >>= 1) {
                const float    ov = __shfl_xor(v, off);
                const unsigned oc = (unsigned)__shfl_xor((int)c, off);
                if (ov > v || (ov == v && oc < c)) { v = ov; c = oc; }
            }
            if (m == 0) atomicMax(best + grow, pack_key(v, c));
        }
    }

    // ---- col-wise argmax (off-diagonal blocks only) ----
    if (bx != by) {
        #pragma unroll
        for (int j = 0; j < 2; ++j) {
            const int gcol = n0 + wcol + j * 32 + m;
            float v = -3.0f; unsigned c = 0xFFFFFFFFu;
            #pragma unroll
            for (int i = 0; i < 2; ++i) {
                #pragma unroll
                for (int reg = 0; reg < 16; ++reg) {
                    const int grow = m0 + wrow + i * 32 + (reg & 3) + 8 * (reg >> 2) + 4 * half;
                    const float val = acc[i][j][reg];
                    if (val > v || (val == v && (unsigned)grow < c)) {
                        v = val; c = (unsigned)grow;
                    }
                }
            }
            // combine the two halves holding the same col
            {
                const float    ov = __shfl_xor(v, 32);
                const unsigned oc = (unsigned)__shfl_xor((int)c, 32);
                if (ov > v || (ov == v && oc < c)) { v = ov; c = oc; }
            }
            if (half == 0) atomicMax(best + gcol, pack_key(v, c));
        }
    }
}

// ---------------- 3) pairwise distance + log -> 256 padded partials ---------
__global__ __launch_bounds__(256) void k_dist(
    const float* __restrict__ in, const float* __restrict__ norms,
    const unsigned long long* __restrict__ best, float* __restrict__ psum, int D)
{
    const int row = blockIdx.x;
    const int t = threadIdx.x;
    const unsigned long long key = best[row];
    const int nb = (int)(~(unsigned)key);        // recover neighbor index
    const float invi = 1.0f / fmaxf(norms[row], KEPS);
    const float invj = 1.0f / fmaxf(norms[nb], KEPS);
    const float4* xi = (const float4*)(in + (size_t)row * D);
    const float4* xj = (const float4*)(in + (size_t)nb * D);
    const float4 a = xi[t], b = xj[t];
    const float dx = a.x * invi - b.x * invj + KEPS;
    const float dy = a.y * invi - b.y * invj + KEPS;
    const float dz = a.z * invi - b.z * invj + KEPS;
    const float dw = a.w * invi - b.w * invj + KEPS;
    float ss = dx*dx + dy*dy + dz*dz + dw*dw;
    for (int off = 32; off; off >>= 1) ss += __shfl_down(ss, off);
    __shared__ float red[4];
    const int lane = t & 63, wave = t >> 6;
    if (lane == 0) red[wave] = ss;
    __syncthreads();
    if (t == 0) {
        const float tot = red[0] + red[1] + red[2] + red[3];
        // scatter over 256 cache-line-padded slots: 64 atomics/slot, no hotspot
        atomicAdd(psum + (row & 255) * 16, logf(sqrtf(tot) + KEPS));
    }
}

// ---------------- 4) finalize: reduce 256 partials --------------------------
__global__ void k_final(const float* __restrict__ psum, float* __restrict__ out, float invN)
{
    const int t = threadIdx.x;                   // 64 threads
    float s = psum[t * 16] + psum[(t + 64) * 16]
            + psum[(t + 128) * 16] + psum[(t + 192) * 16];
    for (int off = 32; off; off >>= 1) s += __shfl_down(s, off);
    if (t == 0) out[0] = -s * invN;
}

extern "C" void kernel_launch(void* const* d_in, const int* in_sizes, int n_in,
                              void* d_out, int out_size, void* d_ws, size_t ws_size,
                              hipStream_t stream)
{
    const float* in = (const float*)d_in[0];
    const int D = 1024;
    const int N = in_sizes[0] / D;               // 16384

    char* ws = (char*)d_ws;
    uchar* xq = (uchar*)ws;                                      // N*D = 16 MiB
    size_t off = (size_t)N * D;
    float* norms = (float*)(ws + off);           off += (size_t)N * 4;
    unsigned long long* best = (unsigned long long*)(ws + off); off += (size_t)N * 8;
    float* psum = (float*)(ws + off);            // 256 slots x 16 floats
    float* out = (float*)d_out;

    k_normalize<<<N, 256, 0, stream>>>(in, xq, norms, best, psum, D);
    const int T = N / BM;                        // 128 tiles per dim
    const int P = T * (T + 1) / 2;               // 8256 upper-tri blocks
    k_gemm_argmax<<<P, 256, 0, stream>>>(xq, best, T);
    k_dist<<<N, 256, 0, stream>>>(in, norms, best, psum, D);
    k_final<<<1, 64, 0, stream>>>(psum, out, 1.0f / (float)N);
}

// Round 11
// 1251.777 us; speedup vs baseline: 1.2504x; 1.2504x over previous
//
#include <hip/hip_runtime.h>

typedef float f32x16 __attribute__((ext_vector_type(16)));
typedef int   i32x8  __attribute__((ext_vector_type(8)));
typedef int   i32x4  __attribute__((ext_vector_type(4)));
typedef unsigned char uchar;

#define KEPS 1e-8f
#define BM 128
#define BN 128
#define BK 64    // one K=64 scaled-MFMA step per kt; 16 K-iterations

// ---------------- 1) row L2-normalize: fp32 norms + fp8 e4m3 copy -----------
__global__ __launch_bounds__(256) void k_normalize(
    const float* __restrict__ in, uchar* __restrict__ xq,
    float* __restrict__ norms, unsigned long long* __restrict__ best,
    float* __restrict__ psum, int D)
{
    const int row = blockIdx.x;
    const int t = threadIdx.x;
    const float4* inr = (const float4*)(in + (size_t)row * D);
    float4 v = inr[t];                       // D=1024 -> 256 float4
    float ss = v.x*v.x + v.y*v.y + v.z*v.z + v.w*v.w;
    for (int off = 32; off; off >>= 1) ss += __shfl_down(ss, off);
    __shared__ float red[4];
    const int lane = t & 63, wave = t >> 6;
    if (lane == 0) red[wave] = ss;
    __syncthreads();
    const float total = red[0] + red[1] + red[2] + red[3];
    const float nrm = sqrtf(total);
    const float inv = 1.0f / fmaxf(nrm, KEPS);
    unsigned r = 0;
    r = __builtin_amdgcn_cvt_pk_fp8_f32(v.x * inv, v.y * inv, r, 0);
    r = __builtin_amdgcn_cvt_pk_fp8_f32(v.z * inv, v.w * inv, r, 1);
    ((unsigned*)(xq + (size_t)row * D))[t] = r;
    if (t == 0) {
        norms[row] = nrm;
        best[row] = 0ull;                    // any real packed key beats 0
    }
    if (row < 256 && t == 1) psum[row * 16] = 0.0f;   // cache-line-padded partials
}

__device__ __forceinline__ unsigned long long pack_key(float v, unsigned idx)
{
    unsigned ub = __float_as_uint(v);
    ub = (ub & 0x80000000u) ? ~ub : (ub | 0x80000000u); // monotonic map
    return ((unsigned long long)ub << 32) | (unsigned long long)(~idx);
}

// ---------------- 2) x x^T triangular MX-fp8 GEMM, dbuf LDS -----------------
// R10 layout verified correct (absmax 0.0); R10's failure was REGISTER SPILL:
// launch_bounds(256,4) = 128-reg unified cap vs acc 64 + frag 32 + addr ~30
// + pipelining copies. Fix: (256,3) -> 170-reg cap, 3 blocks/CU (LDS 96 KB).
// Inner compute: mfma_scale_f32_32x32x64_f8f6f4 with unit scales (e8m0=127),
// 2x the non-scaled fp8 rate. 4 MFMA + 8 ds_read_b128 per kt.
// A/B fragment: m(n)=lane&31, k=(lane>>5)*32+byte. C/D: col=lane&31,
// row=(reg&3)+8*(reg>>2)+4*(lane>>5). All end-to-end verified in R10.
// Triangular covering bx >= by; row-pass + col-pass (off-diag) covers every
// unordered pair; duplicates harmless under idempotent atomicMax.
__global__ __launch_bounds__(256, 3) void k_gemm_argmax(
    const uchar* __restrict__ xq, unsigned long long* __restrict__ best,
    int T)
{
    // triangular mapping: p -> (by, bx), bx >= by
    const int p = blockIdx.x;
    const float tf = (float)T + 0.5f;
    int by = (int)(tf - sqrtf(tf * tf - 2.0f * (float)p));
    while (by > 0 && p < by * T - by * (by - 1) / 2) --by;
    while (p >= (by + 1) * T - (by + 1) * by / 2) ++by;
    const int bx = by + (p - (by * T - by * (by - 1) / 2));

    __shared__ uchar lds[2][(BM + BN) * BK];   // 2 x 16 KiB
    const int t    = threadIdx.x;
    const int lane = t & 63;
    const int wave = t >> 6;
    const int m    = lane & 31;
    const int half = lane >> 5;
    const int wrow = (wave >> 1) * 64;
    const int wcol = (wave & 1) * 64;
    const int m0   = by * BM;
    const int n0   = bx * BN;

    f32x16 acc[2][2] = {};

    // staging: thread t owns stored chunk c = t (rows 0..63) and c = t + 256
    // (rows 64..127) of each panel; stored col = t&3, global col swizzled.
    const int row_s = t >> 2;
    const int col_s = t & 3;
    const int gsw = (col_s ^ ((row_s ^ (row_s >> 2)) & 3)) * 16;  // byte col
    const uchar* aP0 = xq + (size_t)(m0 + row_s) * 1024 + gsw;
    const uchar* bP0 = xq + (size_t)(n0 + row_s) * 1024 + gsw;
    const uchar* aP1 = aP0 + 64 * 1024;
    const uchar* bP1 = bP0 + 64 * 1024;
    const int l16 = t * 16;

#define STAGE(buf, koff)                                                              \
    do {                                                                              \
        __builtin_amdgcn_global_load_lds(                                             \
            (const __attribute__((address_space(1))) void*)(aP0 + (koff)),            \
            (__attribute__((address_space(3))) void*)(&lds[buf][0] + l16), 16, 0, 0); \
        __builtin_amdgcn_global_load_lds(                                             \
            (const __attribute__((address_space(1))) void*)(aP1 + (koff)),            \
            (__attribute__((address_space(3))) void*)(&lds[buf][4096] + l16), 16, 0, 0); \
        __builtin_amdgcn_global_load_lds(                                             \
            (const __attribute__((address_space(1))) void*)(bP0 + (koff)),            \
            (__attribute__((address_space(3))) void*)(&lds[buf][8192] + l16), 16, 0, 0); \
        __builtin_amdgcn_global_load_lds(                                             \
            (const __attribute__((address_space(1))) void*)(bP1 + (koff)),            \
            (__attribute__((address_space(3))) void*)(&lds[buf][12288] + l16), 16, 0, 0); \
    } while (0)

    STAGE(0, 0);
    __syncthreads();

    const unsigned sc1 = 0x7F7F7F7Fu;    // e8m0 = 127 -> scale 2^0 = 1.0

    #pragma unroll
    for (int kt = 0; kt < 16; ++kt) {
        const int cur = kt & 1;
        if (kt < 15) STAGE(cur ^ 1, (kt + 1) * BK);   // K-advance in pointer
        const uchar* Al = &lds[cur][0];
        const uchar* Bl = &lds[cur][8192];
        i32x8 a[2], b[2];
        #pragma unroll
        for (int i = 0; i < 2; ++i) {
            const int row = wrow + i * 32 + m;
            const int sw  = (row ^ (row >> 2)) & 3;
            const uchar* base = Al + row * 64;
            const i32x4 lo = *(const i32x4*)(base + (((2 * half)     ^ sw) * 16));
            const i32x4 hi = *(const i32x4*)(base + (((2 * half + 1) ^ sw) * 16));
            a[i] = i32x8{lo.x, lo.y, lo.z, lo.w, hi.x, hi.y, hi.z, hi.w};
        }
        #pragma unroll
        for (int j = 0; j < 2; ++j) {
            const int row = wcol + j * 32 + m;
            const int sw  = (row ^ (row >> 2)) & 3;
            const uchar* base = Bl + row * 64;
            const i32x4 lo = *(const i32x4*)(base + (((2 * half)     ^ sw) * 16));
            const i32x4 hi = *(const i32x4*)(base + (((2 * half + 1) ^ sw) * 16));
            b[j] = i32x8{lo.x, lo.y, lo.z, lo.w, hi.x, hi.y, hi.z, hi.w};
        }
        #pragma unroll
        for (int i = 0; i < 2; ++i)
            #pragma unroll
            for (int j = 0; j < 2; ++j)
                acc[i][j] = __builtin_amdgcn_mfma_scale_f32_32x32x64_f8f6f4(
                    a[i], b[j], acc[i][j], 0 /*cbsz: fp8*/, 0 /*blgp: fp8*/,
                    0, sc1, 0, sc1);
        __syncthreads();
    }
#undef STAGE

    // ---- row-wise argmax (this wave's 64 rows, over its 64 cols) ----
    // C/D: col = lane&31, row = (reg&3) + 8*(reg>>2) + 4*half.
    #pragma unroll
    for (int i = 0; i < 2; ++i) {
        #pragma unroll
        for (int reg = 0; reg < 16; ++reg) {
            const int grow = m0 + wrow + i * 32 + (reg & 3) + 8 * (reg >> 2) + 4 * half;
            float v = -3.0f; unsigned c = 0xFFFFFFFFu;
            #pragma unroll
            for (int j = 0; j < 2; ++j) {
                const int col = n0 + wcol + j * 32 + m;
                const float val = acc[i][j][reg];
                if (col != grow && (val > v || (val == v && (unsigned)col < c))) {
                    v = val; c = (unsigned)col;
                }
            }
            // reduce across the 32 lanes of this half (xor<32 keeps half)
            for (int off = 16; off; off >>= 1) {
                const float    ov = __shfl_xor(v, off);
                const unsigned oc = (unsigned)__shfl_xor((int)c, off);
                if (ov > v || (ov == v && oc < c)) { v = ov; c = oc; }
            }
            if (m == 0) atomicMax(best + grow, pack_key(v, c));
        }
    }

    // ---- col-wise argmax (off-diagonal blocks only) ----
    if (bx != by) {
        #pragma unroll
        for (int j = 0; j < 2; ++j) {
            const int gcol = n0 + wcol + j * 32 + m;
            float v = -3.0f; unsigned c = 0xFFFFFFFFu;
            #pragma unroll
            for (int i = 0; i < 2; ++i) {
                #pragma unroll
                for (int reg = 0; reg < 16; ++reg) {
                    const int grow = m0 + wrow + i * 32 + (reg & 3) + 8 * (reg >> 2) + 4 * half;
                    const float val = acc[i][j][reg];
                    if (val > v || (val == v && (unsigned)grow < c)) {
                        v = val; c = (unsigned)grow;
                    }
                }
            }
            // combine the two halves holding the same col
            {
                const float    ov = __shfl_xor(v, 32);
                const unsigned oc = (unsigned)__shfl_xor((int)c, 32);
                if (ov > v || (ov == v && oc < c)) { v = ov; c = oc; }
            }
            if (half == 0) atomicMax(best + gcol, pack_key(v, c));
        }
    }
}

// ---------------- 3) pairwise distance + log -> 256 padded partials ---------
__global__ __launch_bounds__(256) void k_dist(
    const float* __restrict__ in, const float* __restrict__ norms,
    const unsigned long long* __restrict__ best, float* __restrict__ psum, int D)
{
    const int row = blockIdx.x;
    const int t = threadIdx.x;
    const unsigned long long key = best[row];
    const int nb = (int)(~(unsigned)key);        // recover neighbor index
    const float invi = 1.0f / fmaxf(norms[row], KEPS);
    const float invj = 1.0f / fmaxf(norms[nb], KEPS);
    const float4* xi = (const float4*)(in + (size_t)row * D);
    const float4* xj = (const float4*)(in + (size_t)nb * D);
    const float4 a = xi[t], b = xj[t];
    const float dx = a.x * invi - b.x * invj + KEPS;
    const float dy = a.y * invi - b.y * invj + KEPS;
    const float dz = a.z * invi - b.z * invj + KEPS;
    const float dw = a.w * invi - b.w * invj + KEPS;
    float ss = dx*dx + dy*dy + dz*dz + dw*dw;
    for (int off = 32; off; off >>= 1) ss += __shfl_down(ss, off);
    __shared__ float red[4];
    const int lane = t & 63, wave = t >> 6;
    if (lane == 0) red[wave] = ss;
    __syncthreads();
    if (t == 0) {
        const float tot = red[0] + red[1] + red[2] + red[3];
        // scatter over 256 cache-line-padded slots: 64 atomics/slot, no hotspot
        atomicAdd(psum + (row & 255) * 16, logf(sqrtf(tot) + KEPS));
    }
}

// ---------------- 4) finalize: reduce 256 partials --------------------------
__global__ void k_final(const float* __restrict__ psum, float* __restrict__ out, float invN)
{
    const int t = threadIdx.x;                   // 64 threads
    float s = psum[t * 16] + psum[(t + 64) * 16]
            + psum[(t + 128) * 16] + psum[(t + 192) * 16];
    for (int off = 32; off; off >>= 1) s += __shfl_down(s, off);
    if (t == 0) out[0] = -s * invN;
}

extern "C" void kernel_launch(void* const* d_in, const int* in_sizes, int n_in,
                              void* d_out, int out_size, void* d_ws, size_t ws_size,
                              hipStream_t stream)
{
    const float* in = (const float*)d_in[0];
    const int D = 1024;
    const int N = in_sizes[0] / D;               // 16384

    char* ws = (char*)d_ws;
    uchar* xq = (uchar*)ws;                                      // N*D = 16 MiB
    size_t off = (size_t)N * D;
    float* norms = (float*)(ws + off);           off += (size_t)N * 4;
    unsigned long long* best = (unsigned long long*)(ws + off); off += (size_t)N * 8;
    float* psum = (float*)(ws + off);            // 256 slots x 16 floats
    float* out = (float*)d_out;

    k_normalize<<<N, 256, 0, stream>>>(in, xq, norms, best, psum, D);
    const int T = N / BM;                        // 128 tiles per dim
    const int P = T * (T + 1) / 2;               // 8256 upper-tri blocks
    k_gemm_argmax<<<P, 256, 0, stream>>>(xq, best, T);
    k_dist<<<N, 256, 0, stream>>>(in, norms, best, psum, D);
    k_final<<<1, 64, 0, stream>>>(psum, out, 1.0f / (float)N);
}

// Round 12
// 438.244 us; speedup vs baseline: 3.5717x; 2.8563x over previous
//
#include <hip/hip_runtime.h>

typedef float f32x16 __attribute__((ext_vector_type(16)));
typedef int   i32x8  __attribute__((ext_vector_type(8)));
typedef int   i32x4  __attribute__((ext_vector_type(4)));
typedef unsigned char uchar;

#define KEPS 1e-8f
#define BM 128
#define BN 128
#define BK 64    // one K=64 scaled-MFMA step per kt; 16 K-iterations

// ---------------- 1) row L2-normalize: fp32 norms + fp8 e4m3 copy -----------
__global__ __launch_bounds__(256) void k_normalize(
    const float* __restrict__ in, uchar* __restrict__ xq,
    float* __restrict__ norms, unsigned long long* __restrict__ best,
    float* __restrict__ psum, int D)
{
    const int row = blockIdx.x;
    const int t = threadIdx.x;
    const float4* inr = (const float4*)(in + (size_t)row * D);
    float4 v = inr[t];                       // D=1024 -> 256 float4
    float ss = v.x*v.x + v.y*v.y + v.z*v.z + v.w*v.w;
    for (int off = 32; off; off >>= 1) ss += __shfl_down(ss, off);
    __shared__ float red[4];
    const int lane = t & 63, wave = t >> 6;
    if (lane == 0) red[wave] = ss;
    __syncthreads();
    const float total = red[0] + red[1] + red[2] + red[3];
    const float nrm = sqrtf(total);
    const float inv = 1.0f / fmaxf(nrm, KEPS);
    unsigned r = 0;
    r = __builtin_amdgcn_cvt_pk_fp8_f32(v.x * inv, v.y * inv, r, 0);
    r = __builtin_amdgcn_cvt_pk_fp8_f32(v.z * inv, v.w * inv, r, 1);
    ((unsigned*)(xq + (size_t)row * D))[t] = r;
    if (t == 0) {
        norms[row] = nrm;
        best[row] = 0ull;                    // any real packed key beats 0
    }
    if (row < 256 && t == 1) psum[row * 16] = 0.0f;   // cache-line-padded partials
}

__device__ __forceinline__ unsigned long long pack_key(float v, unsigned idx)
{
    unsigned ub = __float_as_uint(v);
    ub = (ub & 0x80000000u) ? ~ub : (ub | 0x80000000u); // monotonic map
    return ((unsigned long long)ub << 32) | (unsigned long long)(~idx);
}

// ---------------- 2) x x^T triangular MX-fp8 GEMM, dbuf LDS -----------------
// MX layouts verified end-to-end in R10/R11 (absmax 0.0). R10/R11 regressed
// from REGISTER SPILL caused by full unroll of the 16-iter K-loop (global
// scheduling keeps ~64 temp regs live across iterations, demand > 170 cap).
// Fix: #pragma unroll 1 + pointer-increment staging + runtime buffer select
// -> one iteration's temps live at a time (~145 regs total, fits (256,3)).
// Inner compute: mfma_scale_f32_32x32x64_f8f6f4 with unit scales (e8m0=127),
// 2x the non-scaled fp8 rate. 4 MFMA + 8 ds_read_b128 per kt.
// A/B fragment: m(n)=lane&31, k=(lane>>5)*32+byte. C/D: col=lane&31,
// row=(reg&3)+8*(reg>>2)+4*(lane>>5).
// Triangular covering bx >= by; row-pass + col-pass (off-diag) covers every
// unordered pair; duplicates harmless under idempotent atomicMax.
__global__ __launch_bounds__(256, 3) void k_gemm_argmax(
    const uchar* __restrict__ xq, unsigned long long* __restrict__ best,
    int T)
{
    // triangular mapping: p -> (by, bx), bx >= by
    const int p = blockIdx.x;
    const float tf = (float)T + 0.5f;
    int by = (int)(tf - sqrtf(tf * tf - 2.0f * (float)p));
    while (by > 0 && p < by * T - by * (by - 1) / 2) --by;
    while (p >= (by + 1) * T - (by + 1) * by / 2) ++by;
    const int bx = by + (p - (by * T - by * (by - 1) / 2));

    __shared__ uchar lds[2][(BM + BN) * BK];   // 2 x 16 KiB
    const int t    = threadIdx.x;
    const int lane = t & 63;
    const int wave = t >> 6;
    const int m    = lane & 31;
    const int half = lane >> 5;
    const int wrow = (wave >> 1) * 64;
    const int wcol = (wave & 1) * 64;
    const int m0   = by * BM;
    const int n0   = bx * BN;

    f32x16 acc[2][2] = {};

    // staging: thread t owns stored chunk c = t (rows 0..63) and c = t + 256
    // (rows 64..127) of each panel; stored col = t&3, global col swizzled.
    const int row_s = t >> 2;
    const int col_s = t & 3;
    const int gsw = (col_s ^ ((row_s ^ (row_s >> 2)) & 3)) * 16;  // byte col
    const uchar* aP0 = xq + (size_t)(m0 + row_s) * 1024 + gsw;
    const uchar* bP0 = xq + (size_t)(n0 + row_s) * 1024 + gsw;
    const uchar* aP1 = aP0 + 64 * 1024;
    const uchar* bP1 = bP0 + 64 * 1024;
    const int l16 = t * 16;

    // loop-invariant LDS read byte-offsets (relative to buffer base)
    int aoff[2][2], boff[2][2];   // [tile][lo/hi]
    #pragma unroll
    for (int i = 0; i < 2; ++i) {
        const int ra = wrow + i * 32 + m;
        const int sa = (ra ^ (ra >> 2)) & 3;
        aoff[i][0] = ra * 64 + (((2 * half)     ^ sa) * 16);
        aoff[i][1] = ra * 64 + (((2 * half + 1) ^ sa) * 16);
        const int rb = wcol + i * 32 + m;
        const int sb = (rb ^ (rb >> 2)) & 3;
        boff[i][0] = 8192 + rb * 64 + (((2 * half)     ^ sb) * 16);
        boff[i][1] = 8192 + rb * 64 + (((2 * half + 1) ^ sb) * 16);
    }

#define STAGE(bufbase)                                                                \
    do {                                                                              \
        __builtin_amdgcn_global_load_lds(                                             \
            (const __attribute__((address_space(1))) void*)aP0,                       \
            (__attribute__((address_space(3))) void*)((bufbase) + l16), 16, 0, 0);    \
        __builtin_amdgcn_global_load_lds(                                             \
            (const __attribute__((address_space(1))) void*)aP1,                       \
            (__attribute__((address_space(3))) void*)((bufbase) + 4096 + l16), 16, 0, 0); \
        __builtin_amdgcn_global_load_lds(                                             \
            (const __attribute__((address_space(1))) void*)bP0,                       \
            (__attribute__((address_space(3))) void*)((bufbase) + 8192 + l16), 16, 0, 0); \
        __builtin_amdgcn_global_load_lds(                                             \
            (const __attribute__((address_space(1))) void*)bP1,                       \
            (__attribute__((address_space(3))) void*)((bufbase) + 12288 + l16), 16, 0, 0); \
    } while (0)

    STAGE(&lds[0][0]);
    aP0 += BK; aP1 += BK; bP0 += BK; bP1 += BK;
    __syncthreads();

    const unsigned sc1 = 0x7F7F7F7Fu;    // e8m0 = 127 -> scale 2^0 = 1.0

    #pragma unroll 1
    for (int kt = 0; kt < 16; ++kt) {
        uchar* curb = &lds[kt & 1][0];
        uchar* nxtb = &lds[(kt & 1) ^ 1][0];
        if (kt < 15) {
            STAGE(nxtb);
            aP0 += BK; aP1 += BK; bP0 += BK; bP1 += BK;
        }
        i32x8 a[2], b[2];
        #pragma unroll
        for (int i = 0; i < 2; ++i) {
            const i32x4 lo = *(const i32x4*)(curb + aoff[i][0]);
            const i32x4 hi = *(const i32x4*)(curb + aoff[i][1]);
            a[i] = i32x8{lo.x, lo.y, lo.z, lo.w, hi.x, hi.y, hi.z, hi.w};
        }
        #pragma unroll
        for (int j = 0; j < 2; ++j) {
            const i32x4 lo = *(const i32x4*)(curb + boff[j][0]);
            const i32x4 hi = *(const i32x4*)(curb + boff[j][1]);
            b[j] = i32x8{lo.x, lo.y, lo.z, lo.w, hi.x, hi.y, hi.z, hi.w};
        }
        #pragma unroll
        for (int i = 0; i < 2; ++i)
            #pragma unroll
            for (int j = 0; j < 2; ++j)
                acc[i][j] = __builtin_amdgcn_mfma_scale_f32_32x32x64_f8f6f4(
                    a[i], b[j], acc[i][j], 0 /*cbsz: fp8*/, 0 /*blgp: fp8*/,
                    0, sc1, 0, sc1);
        __syncthreads();
    }
#undef STAGE

    // ---- row-wise argmax (this wave's 64 rows, over its 64 cols) ----
    // C/D: col = lane&31, row = (reg&3) + 8*(reg>>2) + 4*half.
    #pragma unroll
    for (int i = 0; i < 2; ++i) {
        #pragma unroll
        for (int reg = 0; reg < 16; ++reg) {
            const int grow = m0 + wrow + i * 32 + (reg & 3) + 8 * (reg >> 2) + 4 * half;
            float v = -3.0f; unsigned c = 0xFFFFFFFFu;
            #pragma unroll
            for (int j = 0; j < 2; ++j) {
                const int col = n0 + wcol + j * 32 + m;
                const float val = acc[i][j][reg];
                if (col != grow && (val > v || (val == v && (unsigned)col < c))) {
                    v = val; c = (unsigned)col;
                }
            }
            // reduce across the 32 lanes of this half (xor<32 keeps half)
            for (int off = 16; off; off >>= 1) {
                const float    ov = __shfl_xor(v, off);
                const unsigned oc = (unsigned)__shfl_xor((int)c, off);
                if (ov > v || (ov == v && oc < c)) { v = ov; c = oc; }
            }
            if (m == 0) atomicMax(best + grow, pack_key(v, c));
        }
    }

    // ---- col-wise argmax (off-diagonal blocks only) ----
    if (bx != by) {
        #pragma unroll
        for (int j = 0; j < 2; ++j) {
            const int gcol = n0 + wcol + j * 32 + m;
            float v = -3.0f; unsigned c = 0xFFFFFFFFu;
            #pragma unroll
            for (int i = 0; i < 2; ++i) {
                #pragma unroll
                for (int reg = 0; reg < 16; ++reg) {
                    const int grow = m0 + wrow + i * 32 + (reg & 3) + 8 * (reg >> 2) + 4 * half;
                    const float val = acc[i][j][reg];
                    if (val > v || (val == v && (unsigned)grow < c)) {
                        v = val; c = (unsigned)grow;
                    }
                }
            }
            // combine the two halves holding the same col
            {
                const float    ov = __shfl_xor(v, 32);
                const unsigned oc = (unsigned)__shfl_xor((int)c, 32);
                if (ov > v || (ov == v && oc < c)) { v = ov; c = oc; }
            }
            if (half == 0) atomicMax(best + gcol, pack_key(v, c));
        }
    }
}

// ---------------- 3) pairwise distance + log -> 256 padded partials ---------
__global__ __launch_bounds__(256) void k_dist(
    const float* __restrict__ in, const float* __restrict__ norms,
    const unsigned long long* __restrict__ best, float* __restrict__ psum, int D)
{
    const int row = blockIdx.x;
    const int t = threadIdx.x;
    const unsigned long long key = best[row];
    const int nb = (int)(~(unsigned)key);        // recover neighbor index
    const float invi = 1.0f / fmaxf(norms[row], KEPS);
    const float invj = 1.0f / fmaxf(norms[nb], KEPS);
    const float4* xi = (const float4*)(in + (size_t)row * D);
    const float4* xj = (const float4*)(in + (size_t)nb * D);
    const float4 a = xi[t], b = xj[t];
    const float dx = a.x * invi - b.x * invj + KEPS;
    const float dy = a.y * invi - b.y * invj + KEPS;
    const float dz = a.z * invi - b.z * invj + KEPS;
    const float dw = a.w * invi - b.w * invj + KEPS;
    float ss = dx*dx + dy*dy + dz*dz + dw*dw;
    for (int off = 32; off; off >>= 1) ss += __shfl_down(ss, off);
    __shared__ float red[4];
    const int lane = t & 63, wave = t >> 6;
    if (lane == 0) red[wave] = ss;
    __syncthreads();
    if (t == 0) {
        const float tot = red[0] + red[1] + red[2] + red[3];
        // scatter over 256 cache-line-padded slots: 64 atomics/slot, no hotspot
        atomicAdd(psum + (row & 255) * 16, logf(sqrtf(tot) + KEPS));
    }
}

// ---------------- 4) finalize: reduce 256 partials --------------------------
__global__ void k_final(const float* __restrict__ psum, float* __restrict__ out, float invN)
{
    const int t = threadIdx.x;                   // 64 threads
    float s = psum[t * 16] + psum[(t + 64) * 16]
            + psum[(t + 128) * 16] + psum[(t + 192) * 16];
    for (int off = 32; off; off >>= 1) s += __shfl_down(s, off);
    if (t == 0) out[0] = -s * invN;
}

extern "C" void kernel_launch(void* const* d_in, const int* in_sizes, int n_in,
                              void* d_out, int out_size, void* d_ws, size_t ws_size,
                              hipStream_t stream)
{
    const float* in = (const float*)d_in[0];
    const int D = 1024;
    const int N = in_sizes[0] / D;               // 16384

    char* ws = (char*)d_ws;
    uchar* xq = (uchar*)ws;                                      // N*D = 16 MiB
    size_t off = (size_t)N * D;
    float* norms = (float*)(ws + off);           off += (size_t)N * 4;
    unsigned long long* best = (unsigned long long*)(ws + off); off += (size_t)N * 8;
    float* psum = (float*)(ws + off);            // 256 slots x 16 floats
    float* out = (float*)d_out;

    k_normalize<<<N, 256, 0, stream>>>(in, xq, norms, best, psum, D);
    const int T = N / BM;                        // 128 tiles per dim
    const int P = T * (T + 1) / 2;               // 8256 upper-tri blocks
    k_gemm_argmax<<<P, 256, 0, stream>>>(xq, best, T);
    k_dist<<<N, 256, 0, stream>>>(in, norms, best, psum, D);
    k_final<<<1, 64, 0, stream>>>(psum, out, 1.0f / (float)N);
}